// Round 4
// baseline (194.953 us; speedup 1.0000x reference)
//
#include <hip/hip_runtime.h>

#define HW_    56
#define C_     128
#define SHIFT_ 3
#define NH_    4
#define NT_    49

typedef __attribute__((ext_vector_type(8))) __bf16 bf16x8;
typedef __attribute__((ext_vector_type(4))) float  f32x4;

// d_ws layout:
//   shorts [0, 65536)      : wT[384][128] (oc-major) then wpT[128][128]
//   bytes  [131072, +3.2MB): f32 cb[wpos=64][h=4][q=49][k=64]  (bias + mask, post-softmax)
#define WS_CB_BYTE  131072
#define CB_ELEMS    (64 * 4 * 49 * 64)

// LDS (49152 B). 512-thread blocks -> 3 blocks/CU = 24 waves/CU.
//   XB  (16KB): X bf16 frag-order [16 g][64 tok][16B]; after b2 reused as
//               V^T per head h at XB+h*4096: [8 g(tok)][32 d][16B]
//   QKB (32KB): per head h at QKB+h*8192: Q(+0, 4KB), K(+4096, 4KB);
//               P overlays Q+K after softmax; X2 (attn out) overlays K after PV
#define XB    0
#define QKB   16384
#define SMEMB 49152

__device__ __forceinline__ int swz(int g, int row) {          // 1024B-row-group regions
    return ((g << 10) + (row << 4)) ^ ((g & 7) << 4);
}
__device__ __forceinline__ int swzv(int g, int row) {         // 512B-row-group regions (VT)
    return ((g << 9) + (row << 4)) ^ ((g & 7) << 4);
}
__device__ __forceinline__ int x2addr(int g, int tok) {       // X2 over K sub-regions
    return QKB + (g >> 2) * 8192 + 4096 + (g & 3) * 1024 + ((tok << 4) ^ ((g & 7) << 4));
}
__device__ __forceinline__ unsigned short bfbits(float f) {
    __bf16 h = (__bf16)f;
    union { __bf16 b; unsigned short u; } c; c.b = h; return c.u;
}
__device__ __forceinline__ int region(int c) { return c < 49 ? 0 : (c < 53 ? 1 : 2); }

// ---- prep 1: transpose + bf16-convert weights ----
__global__ void prep_weights(const float* __restrict__ wq, const float* __restrict__ wp,
                             unsigned short* __restrict__ ws) {
    int i = blockIdx.x * 256 + threadIdx.x;
    if (i < 49152) {
        int oc = i >> 7, ic = i & 127;
        ws[i] = bfbits(wq[ic * 384 + oc]);
    } else if (i < 65536) {
        int j = i - 49152;
        int oc = j >> 7, ic = j & 127;
        ws[i] = bfbits(wp[ic * 128 + oc]);
    }
}

// ---- prep 2: combined post-softmax bias + shifted-window mask ----
__global__ void prep_bias(const float* __restrict__ rel_table, float* __restrict__ cb) {
    int i = blockIdx.x * 256 + threadIdx.x;
    if (i >= CB_ELEMS) return;
    int k = i & 63;
    int t = i >> 6;          // (wpos*4 + h)*49 + q
    int q = t % 49;
    int u = t / 49;
    int h = u & 3;
    int wpos = u >> 2;
    float v = 0.f;
    if (k < 49) {
        int iq = q / 7, jq = q - 7 * iq;
        int ik = k / 7, jk = k - 7 * ik;
        int wi = wpos >> 3, wj = wpos & 7;
        v = rel_table[((iq - ik + 6) * 13 + (jq - jk + 6)) * NH_ + h];
        int rq = region(wi * 7 + iq) * 3 + region(wj * 7 + jq);
        int rk = region(wi * 7 + ik) * 3 + region(wj * 7 + jk);
        if (rq != rk) v -= 100.0f;
    }
    cb[i] = v;
}

__global__ __launch_bounds__(512, 6)
void swin_fused(const float* __restrict__ x,
                const float* __restrict__ b_qkv,
                const float* __restrict__ b_proj,
                const unsigned short* __restrict__ wsb,
                const float* __restrict__ cb,
                float* __restrict__ out)
{
    extern __shared__ char smc[];
    const __bf16* wt  = (const __bf16*)wsb;           // [384][128]
    const __bf16* wpt = (const __bf16*)(wsb + 49152); // [128][128]

    const int tid = threadIdx.x;
    const int bn  = blockIdx.x;
    const int b   = bn >> 6;
    const int wi  = (bn >> 3) & 7;
    const int wj  = bn & 7;

    const int w  = tid >> 6;        // wave id 0..7
    const int lr = tid & 15;        // lane % 16
    const int lg = (tid & 63) >> 4; // lane / 16

    // ---------------- phase 1: x -> X (bf16 frag-order) ----------------
    {
        const int g  = tid & 15;          // k-group (8 channels)
        const int t0 = tid >> 4;          // 0..31
        #pragma unroll
        for (int p = 0; p < 2; ++p) {
            const int tok = t0 + 32 * p;  // 0..63
            bf16x8* dst = (bf16x8*)(smc + XB + swz(g, tok));
            union { bf16x8 v; __bf16 e[8]; } u;
            if (tok < NT_) {
                const int i1 = tok / 7, j1 = tok - 7 * i1;
                int gh = wi * 7 + i1 + SHIFT_; if (gh >= HW_) gh -= HW_;
                int gw = wj * 7 + j1 + SHIFT_; if (gw >= HW_) gw -= HW_;
                const float* px = x + (((size_t)(b * HW_ + gh)) * HW_ + gw) * C_ + g * 8;
                float4 a0 = *(const float4*)(px);
                float4 a1 = *(const float4*)(px + 4);
                u.e[0] = (__bf16)a0.x; u.e[1] = (__bf16)a0.y;
                u.e[2] = (__bf16)a0.z; u.e[3] = (__bf16)a0.w;
                u.e[4] = (__bf16)a1.x; u.e[5] = (__bf16)a1.y;
                u.e[6] = (__bf16)a1.z; u.e[7] = (__bf16)a1.w;
            } else {
                #pragma unroll
                for (int e = 0; e < 8; ++e) u.e[e] = (__bf16)0.0f;
            }
            *dst = u.v;
        }
    }
    __syncthreads();  // b1

    // ---------------- phase 2: QKV' = Wt @ X^T  (M=384 oc, N=64 tok, K=128) ----------------
    // wave w owns column tiles {w (q), 8+w (k), 16+w (v)}: head w>>1, d-half w&1 each.
    f32x4 acc[3][4];
    {
        #pragma unroll
        for (int i = 0; i < 3; ++i) {
            const int oc0 = (w + 8 * i) * 16 + lg * 4;
            f32x4 bv;
            #pragma unroll
            for (int r = 0; r < 4; ++r) bv[r] = b_qkv[oc0 + r];
            #pragma unroll
            for (int nt = 0; nt < 4; ++nt) acc[i][nt] = bv;
        }
        #pragma unroll
        for (int ks = 0; ks < 4; ++ks) {
            bf16x8 bfr[4];
            #pragma unroll
            for (int nt = 0; nt < 4; ++nt)
                bfr[nt] = *(const bf16x8*)(smc + XB + swz(ks * 4 + lg, nt * 16 + lr));
            #pragma unroll
            for (int i = 0; i < 3; ++i) {
                const int mt = w + 8 * i;
                bf16x8 afr = *(const bf16x8*)(wt + (mt * 16 + lr) * 128 + ks * 32 + lg * 8);
                #pragma unroll
                for (int nt = 0; nt < 4; ++nt)
                    acc[i][nt] = __builtin_amdgcn_mfma_f32_16x16x32_bf16(afr, bfr[nt], acc[i][nt], 0, 0, 0);
            }
        }
        // scatter q (i=0) and k (i=1) into Q/K regions (b64 stores)
        const float qscale = 0.17677669529663687f;
        const int hd = w >> 1;
        const int d0 = (w & 1) * 16 + lg * 4;
        const int g  = d0 >> 3, inner = (d0 & 4) << 1;
        #pragma unroll
        for (int i = 0; i < 2; ++i) {
            const float sc  = (i == 0) ? qscale : 1.0f;
            const int base  = QKB + hd * 8192 + i * 4096;
            #pragma unroll
            for (int nt = 0; nt < 4; ++nt) {
                const int tok = nt * 16 + lr;
                union { short4 s4; __bf16 e[4]; } pk;
                #pragma unroll
                for (int r = 0; r < 4; ++r) pk.e[r] = (__bf16)(acc[i][nt][r] * sc);
                *(short4*)(smc + base + swz(g, tok) + inner) = pk.s4;
            }
        }
    }
    __syncthreads();  // b2: all X reads done; Q/K published
    // V scatter into the now-dead X region (V^T per head)
    {
        const int hd = w >> 1;
        const int d0 = (w & 1) * 16 + lg * 4;
        const int vb2 = XB + hd * 4096;
        #pragma unroll
        for (int nt = 0; nt < 4; ++nt) {
            const int tok = nt * 16 + lr;
            #pragma unroll
            for (int r = 0; r < 4; ++r)
                *(unsigned short*)(smc + vb2 + swzv(tok >> 3, d0 + r) + ((tok & 7) << 1)) =
                    bfbits(acc[2][nt][r]);
        }
    }
    __syncthreads();  // b3: V published

    // ---------------- phase 3: attention; wave pair (2h, 2h+1) = head h, split by q-half ----------------
    {
        const int h   = w >> 1;
        const int nth = (w & 1) << 1;     // my nt blocks: nth, nth+1
        const int qb_ = QKB + h * 8192;
        const int kb_ = qb_ + 4096;
        const int vb_ = XB + h * 4096;
        const float* cbw = cb + (((size_t)(wi * 8 + wj) * 4 + h) * 49) * 64;

        // preload K/Q fragments BEFORE the barrier: partner's P/X2 writes land in
        // the Q/K region; after b4 those bytes are only read at own-q columns.
        bf16x8 ka[4], qf[2];
        #pragma unroll
        for (int mt = 0; mt < 4; ++mt)
            ka[mt] = *(const bf16x8*)(smc + kb_ + swz(lg, mt * 16 + lr));
        #pragma unroll
        for (int j = 0; j < 2; ++j)
            qf[j] = *(const bf16x8*)(smc + qb_ + swz(lg, (nth + j) * 16 + lr));
        __syncthreads();  // b4: all ka/qf reads done; P/X2 overlay now safe

        // S^T = K @ Q^T  (keys x q, K=32)
        f32x4 s[4][2];
        #pragma unroll
        for (int mt = 0; mt < 4; ++mt)
            #pragma unroll
            for (int j = 0; j < 2; ++j) {
                f32x4 z = {0.f, 0.f, 0.f, 0.f};
                s[mt][j] = __builtin_amdgcn_mfma_f32_16x16x32_bf16(ka[mt], qf[j], z, 0, 0, 0);
            }

        // softmax over keys + post-softmax (bias+mask) from cb -> P (bf16, overlays Q+K)
        #pragma unroll
        for (int j = 0; j < 2; ++j) {
            float mx = -3.0e38f;
            #pragma unroll
            for (int mt = 0; mt < 3; ++mt)
                #pragma unroll
                for (int r = 0; r < 4; ++r) mx = fmaxf(mx, s[mt][j][r]);
            if (lg == 0) mx = fmaxf(mx, s[3][j][0]);
            mx = fmaxf(mx, __shfl_xor(mx, 16));
            mx = fmaxf(mx, __shfl_xor(mx, 32));
            float sum = 0.f;
            #pragma unroll
            for (int mt = 0; mt < 3; ++mt)
                #pragma unroll
                for (int r = 0; r < 4; ++r) {
                    const float e = __expf(s[mt][j][r] - mx);
                    s[mt][j][r] = e; sum += e;
                }
            {
                const float e = (lg == 0) ? __expf(s[3][j][0] - mx) : 0.f;
                s[3][j][0] = e;
                sum += e;
            }
            sum += __shfl_xor(sum, 16);
            sum += __shfl_xor(sum, 32);
            const float rs = 1.0f / sum;

            const int q  = (nth + j) * 16 + lr;
            const int qc = (q < NT_) ? q : 48;
            const float* cbq = cbw + qc * 64;

            #pragma unroll
            for (int mt = 0; mt < 4; ++mt) {
                const f32x4 bv = *(const f32x4*)(cbq + mt * 16 + lg * 4);
                union { short4 s4; __bf16 e[4]; } pk;
                #pragma unroll
                for (int r = 0; r < 4; ++r) {
                    const bool valid = (mt < 3) || (lg == 0 && r == 0);
                    const float p = fmaf(s[mt][j][r], rs, bv[r]);
                    pk.e[r] = valid ? (__bf16)p : (__bf16)0.0f;
                }
                const int m0 = mt * 16 + lg * 4;
                *(short4*)(smc + qb_ + swz(m0 >> 3, q) + ((m0 & 4) << 1)) = pk.s4;
            }
        }

        // O^T = VT @ P^T  (d x q, K=64 keys) -> X2 (overlays own head's K, own q cols)
        f32x4 o[2][2];
        #pragma unroll
        for (int mtd = 0; mtd < 2; ++mtd)
            #pragma unroll
            for (int j = 0; j < 2; ++j) { f32x4 z = {0.f,0.f,0.f,0.f}; o[mtd][j] = z; }
        #pragma unroll
        for (int ks = 0; ks < 2; ++ks) {
            bf16x8 va[2], pf[2];
            #pragma unroll
            for (int mtd = 0; mtd < 2; ++mtd)
                va[mtd] = *(const bf16x8*)(smc + vb_ + swzv(ks * 4 + lg, mtd * 16 + lr));
            #pragma unroll
            for (int j = 0; j < 2; ++j)
                pf[j] = *(const bf16x8*)(smc + qb_ + swz(ks * 4 + lg, (nth + j) * 16 + lr));
            #pragma unroll
            for (int mtd = 0; mtd < 2; ++mtd)
                #pragma unroll
                for (int j = 0; j < 2; ++j)
                    o[mtd][j] = __builtin_amdgcn_mfma_f32_16x16x32_bf16(va[mtd], pf[j], o[mtd][j], 0, 0, 0);
        }
        #pragma unroll
        for (int mtd = 0; mtd < 2; ++mtd) {
            const int c0 = h * 32 + mtd * 16 + lg * 4;
            const int g = c0 >> 3, inner = (c0 & 4) << 1;
            #pragma unroll
            for (int j = 0; j < 2; ++j) {
                union { short4 s4; __bf16 e[4]; } pk;
                #pragma unroll
                for (int r = 0; r < 4; ++r) pk.e[r] = (__bf16)o[mtd][j][r];
                *(short4*)(smc + x2addr(g, (nth + j) * 16 + lr) + inner) = pk.s4;
            }
        }
    }
    __syncthreads();  // b5: X2 complete

    // ---------------- phase 4: proj = X2 @ Wp  (M=64 tok, N=128 oc, K=128) + store ----------------
    {
        f32x4 pacc[4];
        const float bv = b_proj[w * 16 + lr];
        #pragma unroll
        for (int mt = 0; mt < 4; ++mt) {
            f32x4 v = {bv, bv, bv, bv};
            pacc[mt] = v;
        }
        #pragma unroll
        for (int ks = 0; ks < 4; ++ks) {
            bf16x8 af[4];
            #pragma unroll
            for (int mt = 0; mt < 4; ++mt)
                af[mt] = *(const bf16x8*)(smc + x2addr(ks * 4 + lg, mt * 16 + lr));
            bf16x8 bfp = *(const bf16x8*)(wpt + (w * 16 + lr) * 128 + ks * 32 + lg * 8);
            #pragma unroll
            for (int mt = 0; mt < 4; ++mt)
                pacc[mt] = __builtin_amdgcn_mfma_f32_16x16x32_bf16(af[mt], bfp, pacc[mt], 0, 0, 0);
        }
        #pragma unroll
        for (int mt = 0; mt < 4; ++mt)
            #pragma unroll
            for (int r = 0; r < 4; ++r) {
                const int tok = mt * 16 + lg * 4 + r;
                if (tok < NT_) {
                    const int i1 = tok / 7, j1 = tok - 7 * i1;
                    int gh = wi * 7 + i1 + SHIFT_; if (gh >= HW_) gh -= HW_;
                    int gw = wj * 7 + j1 + SHIFT_; if (gw >= HW_) gw -= HW_;
                    out[(((size_t)(b * HW_ + gh)) * HW_ + gw) * C_ + w * 16 + lr] = pacc[mt][r];
                }
            }
    }
}

extern "C" void kernel_launch(void* const* d_in, const int* in_sizes, int n_in,
                              void* d_out, int out_size, void* d_ws, size_t ws_size,
                              hipStream_t stream) {
    const float* x      = (const float*)d_in[0];
    const float* w_qkv  = (const float*)d_in[1];
    const float* b_qkv  = (const float*)d_in[2];
    const float* w_proj = (const float*)d_in[3];
    const float* b_proj = (const float*)d_in[4];
    const float* rel    = (const float*)d_in[5];
    float* outp = (float*)d_out;
    unsigned short* wsb = (unsigned short*)d_ws;
    float* cbp = (float*)((char*)d_ws + WS_CB_BYTE);

    hipLaunchKernelGGL(prep_weights, dim3(256), dim3(256), 0, stream, w_qkv, w_proj, wsb);
    hipLaunchKernelGGL(prep_bias, dim3((CB_ELEMS + 255) / 256), dim3(256), 0, stream, rel, cbp);
    hipLaunchKernelGGL(swin_fused, dim3(4096), dim3(512), SMEMB, stream,
                       x, b_qkv, b_proj, wsb, cbp, outp);
}

// Round 5
// 115.457 us; speedup vs baseline: 1.6885x; 1.6885x over previous
//
#include <hip/hip_runtime.h>

#define HW_    56
#define C_     128
#define SHIFT_ 3
#define NH_    4
#define NT_    49

typedef __attribute__((ext_vector_type(8))) __bf16 bf16x8;
typedef __attribute__((ext_vector_type(4))) float  f32x4;

// d_ws layout:
//   shorts [0, 65536)      : wT[384][128] (oc-major) then wpT[128][128]
//   bytes  [131072, +3.2MB): f32 cb[wpos=64][h=4][q=49][k=64]  (bias + mask, post-softmax)
#define WS_CB_BYTE  131072
#define CB_ELEMS    (64 * 4 * 49 * 64)

// LDS 39424 B -> 4 blocks/CU @ 256 thr = 16 waves/CU (vs R3's 48KB/3 blocks).
// [0, 25088): per head h at h*6272: Q [4 g][49 tok][16B] (+0, 3136 B),
//             K (+3136). P [8 kg][49 q][16B] overlays Q+K after frag preload.
// [25088, 39424) = R0 (14336 B):
//   phases 1-2: X [16 g][49 tok][16B] (dead at b2; reads of tok>=49 hit
//               in-bounds garbage, results discarded)
//   after b2:   per head h at R0+h*3584: V^T [7 g(tok-oct)][32 d][16B]
//               (toks 49-55 stored as 0; oct 7 zeroed in-register)
//   after PV:   X2 [4 g][49 tok][16B] overlays own head's V (1 wave/head).
#define QH    6272
#define R0B   25088
#define VH    3584
#define SMEMB 39424

// 784-B-stride layouts (49 rows); XOR keeps group index in range for any G=4/8/16.
__device__ __forceinline__ int q4(int g, int tok) {   // 4- or 16-group regions
    return ((g ^ (tok & 3)) * 784) + (tok << 4);
}
__device__ __forceinline__ int p8(int kg, int q) {    // 8-group P region
    return ((kg ^ (q & 7)) * 784) + (q << 4);
}
__device__ __forceinline__ int swzv(int g, int row) { // V: pow2 rows, old swizzle
    return (((g << 9) + (row << 4)) ^ ((g & 7) << 4));
}
__device__ __forceinline__ unsigned short bfbits(float f) {
    __bf16 h = (__bf16)f;
    union { __bf16 b; unsigned short u; } c; c.b = h; return c.u;
}
__device__ __forceinline__ int region(int c) { return c < 49 ? 0 : (c < 53 ? 1 : 2); }

// ---- prep 1: transpose + bf16-convert weights ----
__global__ void prep_weights(const float* __restrict__ wq, const float* __restrict__ wp,
                             unsigned short* __restrict__ ws) {
    int i = blockIdx.x * 256 + threadIdx.x;
    if (i < 49152) {
        int oc = i >> 7, ic = i & 127;
        ws[i] = bfbits(wq[ic * 384 + oc]);
    } else if (i < 65536) {
        int j = i - 49152;
        int oc = j >> 7, ic = j & 127;
        ws[i] = bfbits(wp[ic * 128 + oc]);
    }
}

// ---- prep 2: combined post-softmax bias + shifted-window mask ----
__global__ void prep_bias(const float* __restrict__ rel_table, float* __restrict__ cb) {
    int i = blockIdx.x * 256 + threadIdx.x;
    if (i >= CB_ELEMS) return;
    int k = i & 63;
    int t = i >> 6;          // (wpos*4 + h)*49 + q
    int q = t % 49;
    int u = t / 49;
    int h = u & 3;
    int wpos = u >> 2;
    float v = 0.f;
    if (k < 49) {
        int iq = q / 7, jq = q - 7 * iq;
        int ik = k / 7, jk = k - 7 * ik;
        int wi = wpos >> 3, wj = wpos & 7;
        v = rel_table[((iq - ik + 6) * 13 + (jq - jk + 6)) * NH_ + h];
        int rq = region(wi * 7 + iq) * 3 + region(wj * 7 + jq);
        int rk = region(wi * 7 + ik) * 3 + region(wj * 7 + jk);
        if (rq != rk) v -= 100.0f;
    }
    cb[i] = v;
}

__global__ __launch_bounds__(256, 4)
void swin_fused(const float* __restrict__ x,
                const float* __restrict__ b_qkv,
                const float* __restrict__ b_proj,
                const unsigned short* __restrict__ wsb,
                const float* __restrict__ cb,
                float* __restrict__ out)
{
    extern __shared__ char smc[];
    const __bf16* wt  = (const __bf16*)wsb;           // [384][128]
    const __bf16* wpt = (const __bf16*)(wsb + 49152); // [128][128]

    const int tid = threadIdx.x;
    const int bn  = blockIdx.x;
    const int b   = bn >> 6;
    const int wi  = (bn >> 3) & 7;
    const int wj  = bn & 7;

    const int w  = tid >> 6;        // wave id 0..3
    const int lr = tid & 15;        // lane % 16
    const int lg = (tid & 63) >> 4; // lane / 16

    // ---------------- phase 1: x -> X (bf16 frag-order, 49 rows) ----------------
    for (int idx = tid; idx < 49 * 16; idx += 256) {
        const int g = idx & 15, tok = idx >> 4;
        const int i1 = tok / 7, j1 = tok - 7 * i1;
        int gh = wi * 7 + i1 + SHIFT_; if (gh >= HW_) gh -= HW_;
        int gw = wj * 7 + j1 + SHIFT_; if (gw >= HW_) gw -= HW_;
        const float* px = x + (((size_t)(b * HW_ + gh)) * HW_ + gw) * C_ + g * 8;
        float4 a0 = *(const float4*)(px);
        float4 a1 = *(const float4*)(px + 4);
        union { bf16x8 v; __bf16 e[8]; } u;
        u.e[0] = (__bf16)a0.x; u.e[1] = (__bf16)a0.y;
        u.e[2] = (__bf16)a0.z; u.e[3] = (__bf16)a0.w;
        u.e[4] = (__bf16)a1.x; u.e[5] = (__bf16)a1.y;
        u.e[6] = (__bf16)a1.z; u.e[7] = (__bf16)a1.w;
        *(bf16x8*)(smc + R0B + q4(g, tok)) = u.v;
    }
    __syncthreads();  // b1

    // ---------------- phase 2: QKV' = Wt @ X^T, two 3-tile passes ----------------
    // wave w owns oc-tiles mt = w + 4*i, i=0..5: {q,q,k,k,v,v}
    const float qscale = 0.17677669529663687f;
    f32x4 accV[2][4];   // v tiles survive past b2

    #pragma unroll
    for (int pass = 0; pass < 2; ++pass) {
        f32x4 acc[3][4];
        #pragma unroll
        for (int i = 0; i < 3; ++i) {
            const int mt = w + 4 * (pass * 3 + i);
            const f32x4 bv = *(const f32x4*)(b_qkv + mt * 16 + lg * 4);
            #pragma unroll
            for (int nt = 0; nt < 4; ++nt) acc[i][nt] = bv;
        }
        #pragma unroll
        for (int ks = 0; ks < 4; ++ks) {
            bf16x8 bfr[4];
            #pragma unroll
            for (int nt = 0; nt < 4; ++nt)
                bfr[nt] = *(const bf16x8*)(smc + R0B + q4(ks * 4 + lg, nt * 16 + lr));
            #pragma unroll
            for (int i = 0; i < 3; ++i) {
                const int mt = w + 4 * (pass * 3 + i);
                bf16x8 afr = *(const bf16x8*)(wt + (mt * 16 + lr) * 128 + ks * 32 + lg * 8);
                #pragma unroll
                for (int nt = 0; nt < 4; ++nt)
                    acc[i][nt] = __builtin_amdgcn_mfma_f32_16x16x32_bf16(afr, bfr[nt], acc[i][nt], 0, 0, 0);
            }
        }
        // scatter q/k tiles now; keep v tiles in regs
        #pragma unroll
        for (int i = 0; i < 3; ++i) {
            const int ti = pass * 3 + i;
            const int mt = w + 4 * ti;
            if (ti < 4) {                       // q (ti 0,1) / k (ti 2,3)
                const int which = mt >> 3;
                const int hd    = (mt >> 1) & 3;
                const int d0    = ((mt & 1) << 4) + lg * 4;
                const float sc  = (which == 0) ? qscale : 1.0f;
                const int base  = hd * QH + which * 3136;
                const int g = d0 >> 3, inner = (d0 & 4) << 1;
                #pragma unroll
                for (int nt = 0; nt < 4; ++nt) {
                    const int tok = nt * 16 + lr;
                    if (tok < NT_) {
                        union { short4 s4; __bf16 e[4]; } pk;
                        #pragma unroll
                        for (int r = 0; r < 4; ++r) pk.e[r] = (__bf16)(acc[i][nt][r] * sc);
                        *(short4*)(smc + base + q4(g, tok) + inner) = pk.s4;
                    }
                }
            } else {                            // v (ti 4,5): stash
                #pragma unroll
                for (int nt = 0; nt < 4; ++nt) accV[ti - 4][nt] = acc[i][nt];
            }
        }
    }
    __syncthreads();  // b2: X reads done; Q/K published

    // V scatter into R0 (X dead) ---- concurrent with K/Q fragment preload
    {
        const int hd = ((w + 16) >> 1) & 3;     // mt=16+w and 20+w share head (w>>1)... recompute per tile
        (void)hd;
        #pragma unroll
        for (int t = 0; t < 2; ++t) {
            const int mt = w + 4 * (4 + t);
            const int hv = (mt >> 1) & 3;
            const int d0 = ((mt & 1) << 4) + lg * 4;
            const int vb2 = R0B + hv * VH;
            #pragma unroll
            for (int nt = 0; nt < 4; ++nt) {
                const int tok = nt * 16 + lr;
                if (tok < 56) {
                    #pragma unroll
                    for (int r = 0; r < 4; ++r) {
                        const unsigned short val =
                            (tok < NT_) ? bfbits(accV[t][nt][r]) : (unsigned short)0;
                        *(unsigned short*)(smc + vb2 + swzv(tok >> 3, d0 + r) + ((tok & 7) << 1)) = val;
                    }
                }
            }
        }
    }

    // ---------------- phase 3: attention, wave = head ----------------
    const int h   = w;
    const int qb_ = h * QH;
    const int kb_ = qb_ + 3136;
    const int vb_ = R0B + h * VH;
    const float* cbw = cb + (((size_t)(wi * 8 + wj) * 4 + h) * 49) * 64;

    // preload K/Q fragments (reads Q/K published at b2; P overlay comes after b3)
    bf16x8 ka[4], qf[4];
    #pragma unroll
    for (int mt = 0; mt < 4; ++mt)
        ka[mt] = *(const bf16x8*)(smc + kb_ + q4(lg, mt * 16 + lr));
    #pragma unroll
    for (int nt = 0; nt < 4; ++nt)
        qf[nt] = *(const bf16x8*)(smc + qb_ + q4(lg, nt * 16 + lr));
    __syncthreads();  // b3: V published; all ka/qf preloads done -> P overlay safe

    {
        // S^T = K @ Q^T  (keys x q, K=32)
        f32x4 s[4][4];
        #pragma unroll
        for (int mt = 0; mt < 4; ++mt)
            #pragma unroll
            for (int nt = 0; nt < 4; ++nt) {
                f32x4 z = {0.f, 0.f, 0.f, 0.f};
                s[mt][nt] = __builtin_amdgcn_mfma_f32_16x16x32_bf16(ka[mt], qf[nt], z, 0, 0, 0);
            }

        // softmax over keys + post-softmax (bias+mask) from cb -> P (overlays Q+K)
        #pragma unroll
        for (int nt = 0; nt < 4; ++nt) {
            float mx = -3.0e38f;
            #pragma unroll
            for (int mt = 0; mt < 3; ++mt)
                #pragma unroll
                for (int r = 0; r < 4; ++r) mx = fmaxf(mx, s[mt][nt][r]);
            if (lg == 0) mx = fmaxf(mx, s[3][nt][0]);
            mx = fmaxf(mx, __shfl_xor(mx, 16));
            mx = fmaxf(mx, __shfl_xor(mx, 32));
            float sum = 0.f;
            #pragma unroll
            for (int mt = 0; mt < 3; ++mt)
                #pragma unroll
                for (int r = 0; r < 4; ++r) {
                    const float e = __expf(s[mt][nt][r] - mx);
                    s[mt][nt][r] = e; sum += e;
                }
            {
                const float e = (lg == 0) ? __expf(s[3][nt][0] - mx) : 0.f;
                s[3][nt][0] = e;
                sum += e;
            }
            sum += __shfl_xor(sum, 16);
            sum += __shfl_xor(sum, 32);
            const float rs = 1.0f / sum;

            const int q  = nt * 16 + lr;
            const int qc = (q < NT_) ? q : 48;
            const float* cbq = cbw + qc * 64;

            #pragma unroll
            for (int mt = 0; mt < 4; ++mt) {
                const f32x4 bv = *(const f32x4*)(cbq + mt * 16 + lg * 4);
                union { short4 s4; __bf16 e[4]; } pk;
                #pragma unroll
                for (int r = 0; r < 4; ++r) {
                    const bool valid = (mt < 3) || (lg == 0 && r == 0);
                    const float p = fmaf(s[mt][nt][r], rs, bv[r]);
                    pk.e[r] = valid ? (__bf16)p : (__bf16)0.0f;
                }
                if (q < NT_) {
                    const int kg = 2 * mt + (lg >> 1);
                    *(short4*)(smc + qb_ + p8(kg, q) + ((lg & 1) << 3)) = pk.s4;
                }
            }
        }

        // O^T = VT @ P^T  (d x q, K=64 keys) -> X2 overlays own head's V
        f32x4 o[2][4];
        #pragma unroll
        for (int mtd = 0; mtd < 2; ++mtd)
            #pragma unroll
            for (int nt = 0; nt < 4; ++nt) { f32x4 z = {0.f,0.f,0.f,0.f}; o[mtd][nt] = z; }
        #pragma unroll
        for (int ks = 0; ks < 2; ++ks) {
            bf16x8 va[2], pf[4];
            #pragma unroll
            for (int mtd = 0; mtd < 2; ++mtd) {
                if (ks * 4 + lg == 7) {
                    union { bf16x8 v; __bf16 e[8]; } z;
                    #pragma unroll
                    for (int e = 0; e < 8; ++e) z.e[e] = (__bf16)0.0f;
                    va[mtd] = z.v;                       // toks 56..63: not stored
                } else {
                    va[mtd] = *(const bf16x8*)(smc + vb_ + swzv(ks * 4 + lg, mtd * 16 + lr));
                }
            }
            #pragma unroll
            for (int nt = 0; nt < 4; ++nt)
                pf[nt] = *(const bf16x8*)(smc + qb_ + p8(ks * 4 + lg, nt * 16 + lr));
            #pragma unroll
            for (int mtd = 0; mtd < 2; ++mtd)
                #pragma unroll
                for (int nt = 0; nt < 4; ++nt)
                    o[mtd][nt] = __builtin_amdgcn_mfma_f32_16x16x32_bf16(va[mtd], pf[nt], o[mtd][nt], 0, 0, 0);
        }
        // X2 scatter into own head's V region (this wave's V reads are done)
        #pragma unroll
        for (int mtd = 0; mtd < 2; ++mtd) {
            const int gl = (mtd * 2 + (lg >> 1)) & 3;
            const int inner = (lg & 1) << 3;
            #pragma unroll
            for (int nt = 0; nt < 4; ++nt) {
                const int tok = nt * 16 + lr;
                if (tok < NT_) {
                    union { short4 s4; __bf16 e[4]; } pk;
                    #pragma unroll
                    for (int r = 0; r < 4; ++r) pk.e[r] = (__bf16)o[mtd][nt][r];
                    *(short4*)(smc + vb_ + q4(gl, tok) + inner) = pk.s4;
                }
            }
        }
    }

    // hoist proj weight fragments (global, no LDS dep) before the barrier
    bf16x8 bfpR[2][4];
    #pragma unroll
    for (int ntl = 0; ntl < 2; ++ntl)
        #pragma unroll
        for (int ks = 0; ks < 4; ++ks)
            bfpR[ntl][ks] = *(const bf16x8*)(wpt + ((w * 2 + ntl) * 16 + lr) * 128 + ks * 32 + lg * 8);
    __syncthreads();  // b4: X2 complete

    // ---------------- phase 4: proj = X2 @ Wp + store ----------------
    {
        f32x4 pacc[4][2];
        #pragma unroll
        for (int ntl = 0; ntl < 2; ++ntl) {
            const float bv = b_proj[(w * 2 + ntl) * 16 + lr];
            #pragma unroll
            for (int mt = 0; mt < 4; ++mt) {
                f32x4 v = {bv, bv, bv, bv};
                pacc[mt][ntl] = v;
            }
        }
        #pragma unroll
        for (int ks = 0; ks < 4; ++ks) {
            bf16x8 af[4];
            #pragma unroll
            for (int mt = 0; mt < 4; ++mt) {
                const int g = ks * 4 + lg;
                af[mt] = *(const bf16x8*)(smc + R0B + (g >> 2) * VH + q4(g & 3, mt * 16 + lr));
            }
            #pragma unroll
            for (int mt = 0; mt < 4; ++mt)
                #pragma unroll
                for (int ntl = 0; ntl < 2; ++ntl)
                    pacc[mt][ntl] = __builtin_amdgcn_mfma_f32_16x16x32_bf16(af[mt], bfpR[ntl][ks], pacc[mt][ntl], 0, 0, 0);
        }
        #pragma unroll
        for (int mt = 0; mt < 4; ++mt)
            #pragma unroll
            for (int r = 0; r < 4; ++r) {
                const int tok = mt * 16 + lg * 4 + r;
                if (tok < NT_) {
                    const int i1 = tok / 7, j1 = tok - 7 * i1;
                    int gh = wi * 7 + i1 + SHIFT_; if (gh >= HW_) gh -= HW_;
                    int gw = wj * 7 + j1 + SHIFT_; if (gw >= HW_) gw -= HW_;
                    float* po = out + (((size_t)(b * HW_ + gh)) * HW_ + gw) * C_;
                    #pragma unroll
                    for (int ntl = 0; ntl < 2; ++ntl)
                        po[(w * 2 + ntl) * 16 + lr] = pacc[mt][ntl][r];
                }
            }
    }
}

extern "C" void kernel_launch(void* const* d_in, const int* in_sizes, int n_in,
                              void* d_out, int out_size, void* d_ws, size_t ws_size,
                              hipStream_t stream) {
    const float* x      = (const float*)d_in[0];
    const float* w_qkv  = (const float*)d_in[1];
    const float* b_qkv  = (const float*)d_in[2];
    const float* w_proj = (const float*)d_in[3];
    const float* b_proj = (const float*)d_in[4];
    const float* rel    = (const float*)d_in[5];
    float* outp = (float*)d_out;
    unsigned short* wsb = (unsigned short*)d_ws;
    float* cbp = (float*)((char*)d_ws + WS_CB_BYTE);

    hipLaunchKernelGGL(prep_weights, dim3(256), dim3(256), 0, stream, w_qkv, w_proj, wsb);
    hipLaunchKernelGGL(prep_bias, dim3((CB_ELEMS + 255) / 256), dim3(256), 0, stream, rel, cbp);
    hipLaunchKernelGGL(swin_fused, dim3(4096), dim3(256), SMEMB, stream,
                       x, b_qkv, b_proj, wsb, cbp, outp);
}